// Round 2
// baseline (263.655 us; speedup 1.0000x reference)
//
#include <hip/hip_runtime.h>

// (B,C,H,W) = (4,16,320,640), fp32 throughout.
constexpr int Bn = 4;
constexpr int Cn = 16;
constexpr int Hn = 320;
constexpr int Wn = 640;
constexpr int NCOL = Bn * Cn * Wn;   // 40960 vertical columns
constexpr int NROW = Bn * Cn * Hn;   // 20480 horizontal rows

// ---------------------------------------------------------------------------
// Vertical, both directions fused fully in registers, ONE store.
// Block = 1024 threads = 16 waves; wave s owns rows [s*20, s*20+20) of the
// same 64 consecutive columns for BOTH directions.
//
// Round-1 lesson: array-based scan state (float y[20] etc.) was demoted to
// scratch by promote-alloca even with a 128-VGPR cap (rocprof VGPR_Count=52
// vs >=80 live values needed) -> kernel was scratch-latency-bound (VALUBusy
// 6%, 1.8 TB/s). This version uses macro-generated NAMED SCALARS: no alloca
// exists, so the state is SSA values and must be register-allocated.
//
// Structure: local DOWN scan (ascending, loads x+g0, keeps x in regs) ->
// local UP scan (descending, loads g1, reuses register x) -> ONE barrier ->
// wave0 stitches DOWN carries while wave1 stitches UP carries (concurrent
// serial stitches) -> ONE barrier -> fused fixup of both directions +
// single coalesced store of max(r_down, r_up).
// Recurrence: y = g*y_prev + x*(1-g) == fma(g, y_prev - x, x); g:=0 at head.
// ---------------------------------------------------------------------------
constexpr int HS = 20;               // rows per segment (320 = 16*20)
constexpr int NS = 16;               // segments = waves per block
constexpr int GPW = Wn / 64;         // 10 column-groups per image width

#define REP20(M) M(0) M(1) M(2) M(3) M(4) M(5) M(6) M(7) M(8) M(9) \
                 M(10) M(11) M(12) M(13) M(14) M(15) M(16) M(17) M(18) M(19)
#define REP20R(M) M(19) M(18) M(17) M(16) M(15) M(14) M(13) M(12) M(11) M(10) \
                  M(9) M(8) M(7) M(6) M(5) M(4) M(3) M(2) M(1) M(0)

__global__ __launch_bounds__(1024, 4) void vert_both(
    const float* __restrict__ x, const float* __restrict__ g0,
    const float* __restrict__ g1, float* __restrict__ vm) {
  __shared__ float Ad[NS][64], Bd[NS][64], Au[NS][64], Bu[NS][64];  // 16 KB
  const int grp = blockIdx.x;              // 640 groups
  const int bc = grp / GPW;
  const int w0 = (grp % GPW) * 64;
  const int s = threadIdx.x >> 6;
  const int l = threadIdx.x & 63;
  const int colbase = bc * (Hn * Wn) + w0 + l;   // < 2^24, int is fine
  const int base = colbase + (s * HS) * Wn;

  // Named scalar scan state (no arrays -> no alloca -> must live in VGPRs).
#define DECL(i) float xl##i, rd##i, pd##i, yu##i, pu##i;
  REP20(DECL)
#undef DECL

  // ---- local DOWN scan (g0, rows ascending); x parked in registers ----
  {
    int off = base;
    float yy = 0.0f, pp = 1.0f;
#define DSTEP(i)                                                      \
    {                                                                 \
      xl##i = x[off];                                                 \
      float gv = g0[off];                                             \
      float bb = (s == 0 && i == 0) ? 0.0f : gv;                      \
      yy = fmaf(bb, yy - xl##i, xl##i);                               \
      pp *= bb;                                                       \
      rd##i = yy;                                                     \
      pd##i = pp;                                                     \
      off += Wn;                                                      \
    }
    REP20(DSTEP)
#undef DSTEP
    Ad[s][l] = yy;
    Bd[s][l] = pp;
  }

  // ---- local UP scan (g1, rows descending); reuses register x ----
  {
    int off = base + (HS - 1) * Wn;
    float yy = 0.0f, pp = 1.0f;
#define USTEP(i)                                                      \
    {                                                                 \
      float gv = g1[off];                                             \
      float bb = (s == NS - 1 && i == HS - 1) ? 0.0f : gv;            \
      yy = fmaf(bb, yy - xl##i, xl##i);                               \
      pp *= bb;                                                       \
      yu##i = yy;                                                     \
      pu##i = pp;                                                     \
      off -= Wn;                                                      \
    }
    REP20R(USTEP)
#undef USTEP
    Au[s][l] = yy;
    Bu[s][l] = pp;
  }
  __syncthreads();

  // ---- concurrent serial carry stitches: wave0 = DOWN, wave1 = UP ----
  if (s == 0) {
    float c = 0.0f;
#pragma unroll
    for (int ss = 0; ss < NS; ++ss) {
      float a = Ad[ss][l], b = Bd[ss][l];
      Ad[ss][l] = c;                       // carry-in for segment ss
      c = fmaf(b, c, a);
    }
  } else if (s == 1) {
    float c = 0.0f;
#pragma unroll
    for (int ss = NS - 1; ss >= 0; --ss) {
      float a = Au[ss][l], b = Bu[ss][l];
      Au[ss][l] = c;                       // carry-in from below
      c = fmaf(b, c, a);
    }
  }
  __syncthreads();

  // ---- fused fixup (both directions) + single coalesced store ----
  {
    const float cd = Ad[s][l];
    const float cu = Au[s][l];
    int off = base;
#define FSTEP(i)                                                      \
    {                                                                 \
      float d = fmaf(pd##i, cd, rd##i);                               \
      float u = fmaf(pu##i, cu, yu##i);                               \
      vm[off] = fmaxf(d, u);                                          \
      off += Wn;                                                      \
    }
    REP20(FSTEP)
#undef FSTEP
  }
}

// ---------------------------------------------------------------------------
// Horizontal + final: block = 256 threads = 4 waves, 4 consecutive rows.
// Stage x/g2/g3 into LDS with coalesced float4 loads; prefetch vm(=out) into
// registers at the same time. One wave per row does the lane-segmented scan
// (WSEG=10) from LDS with one 6-step shuffle scan of (A,B) per direction.
// Final: out = max(r_right, r_left, vm) — same lines this block read.
// ---------------------------------------------------------------------------
constexpr int WSEG = 10;                   // 64 lanes * 10 = 640

__global__ __launch_bounds__(256) void horiz_final(
    const float* __restrict__ x, const float* __restrict__ g2,
    const float* __restrict__ g3, const float* __restrict__ vm,
    float* __restrict__ out) {
  __shared__ float xs[4 * Wn], rrs[4 * Wn], rls[4 * Wn];   // 30 KB
  const int tid = threadIdx.x, wv = tid >> 6, l = tid & 63;
  const size_t rowbase = (size_t)blockIdx.x * 4 * Wn;      // 4 rows contiguous

  const float4* xg = (const float4*)(x + rowbase);
  const float4* g2g = (const float4*)(g2 + rowbase);
  const float4* g3g = (const float4*)(g3 + rowbase);
  const float4* vm4 = (const float4*)(vm + rowbase);
  float4* xsv = (float4*)xs;
  float4* rrv = (float4*)rrs;
  float4* rlv = (float4*)rls;

  // ---- stage (coalesced float4); vm prefetched into registers ----
  const int i0 = tid, i1 = tid + 256, i2 = tid + 512;      // i2 valid if tid<128
  float4 v0, v1, v2;
  xsv[i0] = xg[i0]; rrv[i0] = g2g[i0]; rlv[i0] = g3g[i0]; v0 = vm4[i0];
  xsv[i1] = xg[i1]; rrv[i1] = g2g[i1]; rlv[i1] = g3g[i1]; v1 = vm4[i1];
  if (i2 < Wn) { xsv[i2] = xg[i2]; rrv[i2] = g2g[i2]; rlv[i2] = g3g[i2]; v2 = vm4[i2]; }
  __syncthreads();

  const int rb = wv * Wn + l * WSEG;
  float xl[WSEG], gl[WSEG], yl[WSEG], pl[WSEG];
#pragma unroll
  for (int i = 0; i < WSEG; ++i) { xl[i] = xs[rb + i]; gl[i] = rrs[rb + i]; }

  // ---- forward (r_right) ----
  {
    float y = 0.0f, p = 1.0f;
#pragma unroll
    for (int i = 0; i < WSEG; ++i) {
      float bb = (l == 0 && i == 0) ? 0.0f : gl[i];
      y = fmaf(bb, y - xl[i], xl[i]);
      p *= bb;
      yl[i] = y; pl[i] = p;
    }
    float A = y, B = p;
#pragma unroll
    for (int off = 1; off < 64; off <<= 1) {
      float Au = __shfl_up(A, off);
      float Bu = __shfl_up(B, off);
      if (l >= off) { A = fmaf(B, Au, A); B *= Bu; }
    }
    float c = __shfl_up(A, 1);
    if (l == 0) c = 0.0f;
#pragma unroll
    for (int i = 0; i < WSEG; ++i) rrs[rb + i] = fmaf(pl[i], c, yl[i]);
  }

  // ---- backward (r_left) ----
#pragma unroll
  for (int i = 0; i < WSEG; ++i) gl[i] = rls[rb + i];
  {
    float y = 0.0f, p = 1.0f;
#pragma unroll
    for (int i = WSEG - 1; i >= 0; --i) {
      float bb = (l == 63 && i == WSEG - 1) ? 0.0f : gl[i];
      y = fmaf(bb, y - xl[i], xl[i]);
      p *= bb;
      yl[i] = y; pl[i] = p;
    }
    float A = y, B = p;
#pragma unroll
    for (int off = 1; off < 64; off <<= 1) {
      float Ad = __shfl_down(A, off);
      float Bd = __shfl_down(B, off);
      if (l + off < 64) { A = fmaf(B, Ad, A); B *= Bd; }
    }
    float c = __shfl_down(A, 1);
    if (l == 63) c = 0.0f;
#pragma unroll
    for (int i = 0; i < WSEG; ++i) rls[rb + i] = fmaf(pl[i], c, yl[i]);
  }
  __syncthreads();

  // ---- fused final max + store (coalesced float4) ----
  float4* o4 = (float4*)(out + rowbase);
  {
    float4 a = rrv[i0], b = rlv[i0];
    float4 o;
    o.x = fmaxf(fmaxf(a.x, b.x), v0.x);
    o.y = fmaxf(fmaxf(a.y, b.y), v0.y);
    o.z = fmaxf(fmaxf(a.z, b.z), v0.z);
    o.w = fmaxf(fmaxf(a.w, b.w), v0.w);
    o4[i0] = o;
  }
  {
    float4 a = rrv[i1], b = rlv[i1];
    float4 o;
    o.x = fmaxf(fmaxf(a.x, b.x), v1.x);
    o.y = fmaxf(fmaxf(a.y, b.y), v1.y);
    o.z = fmaxf(fmaxf(a.z, b.z), v1.z);
    o.w = fmaxf(fmaxf(a.w, b.w), v1.w);
    o4[i1] = o;
  }
  if (i2 < Wn) {
    float4 a = rrv[i2], b = rlv[i2];
    float4 o;
    o.x = fmaxf(fmaxf(a.x, b.x), v2.x);
    o.y = fmaxf(fmaxf(a.y, b.y), v2.y);
    o.z = fmaxf(fmaxf(a.z, b.z), v2.z);
    o.w = fmaxf(fmaxf(a.w, b.w), v2.w);
    o4[i2] = o;
  }
}

extern "C" void kernel_launch(void* const* d_in, const int* in_sizes, int n_in,
                              void* d_out, int out_size, void* d_ws,
                              size_t ws_size, hipStream_t stream) {
  const float* x = (const float*)d_in[0];
  const float* g0 = (const float*)d_in[1];
  const float* g1 = (const float*)d_in[2];
  const float* g2 = (const float*)d_in[3];
  const float* g3 = (const float*)d_in[4];
  float* out = (float*)d_out;

  // vert_both writes max(r_down, r_up) into out (single store, both
  // directions fused in registers); horiz_final consumes it (block-local
  // lines) and overwrites with the final 4-way max. No ws use.
  vert_both<<<NCOL / 64, 1024, 0, stream>>>(x, g0, g1, out);
  horiz_final<<<NROW / 4, 256, 0, stream>>>(x, g2, g3, out, out);
}

// Round 5
// 262.935 us; speedup vs baseline: 1.0027x; 1.0027x over previous
//
#include <hip/hip_runtime.h>

// (B,C,H,W) = (4,16,320,640), fp32 throughout.
constexpr int Bn = 4;
constexpr int Cn = 16;
constexpr int Hn = 320;
constexpr int Wn = 640;
constexpr int NCOL = Bn * Cn * Wn;   // 40960 vertical columns
constexpr int NROW = Bn * Cn * Hn;   // 20480 horizontal rows

// ---------------------------------------------------------------------------
// Vertical, both directions fused in registers, ONE store.
// Round-2 lesson: with HS=20 the ~88 live floats/thread exceed the 64-VGPR
// budget the backend actually allocates for (it targets 8 waves/EU and
// spills, VGPR_Count=52..56 across 3 variants; dur pinned at ~71us,
// VALUBusy 6% = scratch-latency-bound). Fix: shrink per-thread state.
//
// Block = 1024 threads = 32 segments x 32 columns (HS=10 rows/thread).
// Live state across the stitch barrier: rd/pd/yu/pu (40) + xl overlap +
// temps ~= 55 floats -> fits under 64 VGPRs at ANY occupancy target.
//
// Structure: local DOWN scan (loads x+g0, x parked in regs) -> local UP
// scan (loads g1, reuses reg x) -> barrier -> concurrent serial stitches
// (wave0 lower half = DOWN, wave1 lower half = UP; different SIMDs) ->
// barrier -> fused fixup + single coalesced store of max(r_down, r_up).
// Recurrence: y = g*y_prev + x*(1-g) == fma(g, y_prev - x, x); g:=0 at head.
// ---------------------------------------------------------------------------
constexpr int HS = 10;               // rows per segment (320 = 32*10)
constexpr int NS = 32;               // segments per column
constexpr int CPB = 32;              // columns per block
constexpr int GPW = Wn / CPB;        // 20 column-groups per image width

#define REP10(M) M(0) M(1) M(2) M(3) M(4) M(5) M(6) M(7) M(8) M(9)
#define REP10R(M) M(9) M(8) M(7) M(6) M(5) M(4) M(3) M(2) M(1) M(0)

__global__ __launch_bounds__(1024, 4) void vert_both(
    const float* __restrict__ x, const float* __restrict__ g0,
    const float* __restrict__ g1, float* __restrict__ vm) {
  __shared__ float Ad[NS][CPB], Bd[NS][CPB], Au[NS][CPB], Bu[NS][CPB]; // 16 KB
  const int grp = blockIdx.x;              // 1280 groups
  const int bc = grp / GPW;
  const int w0 = (grp % GPW) * CPB;
  const int s = threadIdx.x >> 5;          // segment 0..31
  const int l = threadIdx.x & 31;          // column-in-group 0..31
  const int colbase = bc * (Hn * Wn) + w0 + l;   // < 2^24, int is fine
  const int base = colbase + (s * HS) * Wn;

  // Named scalar scan state (no arrays -> no alloca; ~55 live values).
#define DECL(i) float xl##i, rd##i, pd##i, yu##i, pu##i;
  REP10(DECL)
#undef DECL

  // ---- local DOWN scan (g0, rows ascending); x parked in registers ----
  {
    int off = base;
    float yy = 0.0f, pp = 1.0f;
#define DSTEP(i)                                                      \
    {                                                                 \
      xl##i = x[off];                                                 \
      float gv = g0[off];                                             \
      float bb = (s == 0 && i == 0) ? 0.0f : gv;                      \
      yy = fmaf(bb, yy - xl##i, xl##i);                               \
      pp *= bb;                                                       \
      rd##i = yy;                                                     \
      pd##i = pp;                                                     \
      off += Wn;                                                      \
    }
    REP10(DSTEP)
#undef DSTEP
    Ad[s][l] = yy;
    Bd[s][l] = pp;
  }

  // ---- local UP scan (g1, rows descending); reuses register x ----
  {
    int off = base + (HS - 1) * Wn;
    float yy = 0.0f, pp = 1.0f;
#define USTEP(i)                                                      \
    {                                                                 \
      float gv = g1[off];                                             \
      float bb = (s == NS - 1 && i == HS - 1) ? 0.0f : gv;            \
      yy = fmaf(bb, yy - xl##i, xl##i);                               \
      pp *= bb;                                                       \
      yu##i = yy;                                                     \
      pu##i = pp;                                                     \
      off -= Wn;                                                      \
    }
    REP10R(USTEP)
#undef USTEP
    Au[s][l] = yy;
    Bu[s][l] = pp;
  }
  __syncthreads();

  // ---- concurrent serial carry stitches on different waves ----
  if (s == 0) {                            // wave 0, lanes 0-31: DOWN
    float c = 0.0f;
#pragma unroll
    for (int ss = 0; ss < NS; ++ss) {
      float a = Ad[ss][l], b = Bd[ss][l];
      Ad[ss][l] = c;                       // carry-in for segment ss
      c = fmaf(b, c, a);
    }
  } else if (s == 2) {                     // wave 1, lanes 0-31: UP
    float c = 0.0f;
#pragma unroll
    for (int ss = NS - 1; ss >= 0; --ss) {
      float a = Au[ss][l], b = Bu[ss][l];
      Au[ss][l] = c;                       // carry-in from below
      c = fmaf(b, c, a);
    }
  }
  __syncthreads();

  // ---- fused fixup (both directions) + single coalesced store ----
  {
    const float cd = Ad[s][l];
    const float cu = Au[s][l];
    int off = base;
#define FSTEP(i)                                                      \
    {                                                                 \
      float d = fmaf(pd##i, cd, rd##i);                               \
      float u = fmaf(pu##i, cu, yu##i);                               \
      vm[off] = fmaxf(d, u);                                          \
      off += Wn;                                                      \
    }
    REP10(FSTEP)
#undef FSTEP
  }
}

// ---------------------------------------------------------------------------
// Horizontal + final: block = 256 threads = 4 waves, 4 consecutive rows.
// Stage x/g2/g3 into LDS with coalesced float4 loads; prefetch vm(=out) into
// registers at the same time. One wave per row does the lane-segmented scan
// (WSEG=10) from LDS with one 6-step shuffle scan of (A,B) per direction.
// Final: out = max(r_right, r_left, vm) — same lines this block read.
// ---------------------------------------------------------------------------
constexpr int WSEG = 10;                   // 64 lanes * 10 = 640

__global__ __launch_bounds__(256) void horiz_final(
    const float* __restrict__ x, const float* __restrict__ g2,
    const float* __restrict__ g3, const float* __restrict__ vm,
    float* __restrict__ out) {
  __shared__ float xs[4 * Wn], rrs[4 * Wn], rls[4 * Wn];   // 30 KB
  const int tid = threadIdx.x, wv = tid >> 6, l = tid & 63;
  const size_t rowbase = (size_t)blockIdx.x * 4 * Wn;      // 4 rows contiguous

  const float4* xg = (const float4*)(x + rowbase);
  const float4* g2g = (const float4*)(g2 + rowbase);
  const float4* g3g = (const float4*)(g3 + rowbase);
  const float4* vm4 = (const float4*)(vm + rowbase);
  float4* xsv = (float4*)xs;
  float4* rrv = (float4*)rrs;
  float4* rlv = (float4*)rls;

  // ---- stage (coalesced float4); vm prefetched into registers ----
  const int i0 = tid, i1 = tid + 256, i2 = tid + 512;      // i2 valid if tid<128
  float4 v0, v1, v2;
  xsv[i0] = xg[i0]; rrv[i0] = g2g[i0]; rlv[i0] = g3g[i0]; v0 = vm4[i0];
  xsv[i1] = xg[i1]; rrv[i1] = g2g[i1]; rlv[i1] = g3g[i1]; v1 = vm4[i1];
  if (i2 < Wn) { xsv[i2] = xg[i2]; rrv[i2] = g2g[i2]; rlv[i2] = g3g[i2]; v2 = vm4[i2]; }
  __syncthreads();

  const int rb = wv * Wn + l * WSEG;
  float xl[WSEG], gl[WSEG], yl[WSEG], pl[WSEG];
#pragma unroll
  for (int i = 0; i < WSEG; ++i) { xl[i] = xs[rb + i]; gl[i] = rrs[rb + i]; }

  // ---- forward (r_right) ----
  {
    float y = 0.0f, p = 1.0f;
#pragma unroll
    for (int i = 0; i < WSEG; ++i) {
      float bb = (l == 0 && i == 0) ? 0.0f : gl[i];
      y = fmaf(bb, y - xl[i], xl[i]);
      p *= bb;
      yl[i] = y; pl[i] = p;
    }
    float A = y, B = p;
#pragma unroll
    for (int off = 1; off < 64; off <<= 1) {
      float Au = __shfl_up(A, off);
      float Bu = __shfl_up(B, off);
      if (l >= off) { A = fmaf(B, Au, A); B *= Bu; }
    }
    float c = __shfl_up(A, 1);
    if (l == 0) c = 0.0f;
#pragma unroll
    for (int i = 0; i < WSEG; ++i) rrs[rb + i] = fmaf(pl[i], c, yl[i]);
  }

  // ---- backward (r_left) ----
#pragma unroll
  for (int i = 0; i < WSEG; ++i) gl[i] = rls[rb + i];
  {
    float y = 0.0f, p = 1.0f;
#pragma unroll
    for (int i = WSEG - 1; i >= 0; --i) {
      float bb = (l == 63 && i == WSEG - 1) ? 0.0f : gl[i];
      y = fmaf(bb, y - xl[i], xl[i]);
      p *= bb;
      yl[i] = y; pl[i] = p;
    }
    float A = y, B = p;
#pragma unroll
    for (int off = 1; off < 64; off <<= 1) {
      float Ad = __shfl_down(A, off);
      float Bd = __shfl_down(B, off);
      if (l + off < 64) { A = fmaf(B, Ad, A); B *= Bd; }
    }
    float c = __shfl_down(A, 1);
    if (l == 63) c = 0.0f;
#pragma unroll
    for (int i = 0; i < WSEG; ++i) rls[rb + i] = fmaf(pl[i], c, yl[i]);
  }
  __syncthreads();

  // ---- fused final max + store (coalesced float4) ----
  float4* o4 = (float4*)(out + rowbase);
  {
    float4 a = rrv[i0], b = rlv[i0];
    float4 o;
    o.x = fmaxf(fmaxf(a.x, b.x), v0.x);
    o.y = fmaxf(fmaxf(a.y, b.y), v0.y);
    o.z = fmaxf(fmaxf(a.z, b.z), v0.z);
    o.w = fmaxf(fmaxf(a.w, b.w), v0.w);
    o4[i0] = o;
  }
  {
    float4 a = rrv[i1], b = rlv[i1];
    float4 o;
    o.x = fmaxf(fmaxf(a.x, b.x), v1.x);
    o.y = fmaxf(fmaxf(a.y, b.y), v1.y);
    o.z = fmaxf(fmaxf(a.z, b.z), v1.z);
    o.w = fmaxf(fmaxf(a.w, b.w), v1.w);
    o4[i1] = o;
  }
  if (i2 < Wn) {
    float4 a = rrv[i2], b = rlv[i2];
    float4 o;
    o.x = fmaxf(fmaxf(a.x, b.x), v2.x);
    o.y = fmaxf(fmaxf(a.y, b.y), v2.y);
    o.z = fmaxf(fmaxf(a.z, b.z), v2.z);
    o.w = fmaxf(fmaxf(a.w, b.w), v2.w);
    o4[i2] = o;
  }
}

extern "C" void kernel_launch(void* const* d_in, const int* in_sizes, int n_in,
                              void* d_out, int out_size, void* d_ws,
                              size_t ws_size, hipStream_t stream) {
  const float* x = (const float*)d_in[0];
  const float* g0 = (const float*)d_in[1];
  const float* g1 = (const float*)d_in[2];
  const float* g2 = (const float*)d_in[3];
  const float* g3 = (const float*)d_in[4];
  float* out = (float*)d_out;

  // vert_both writes max(r_down, r_up) into out (single store, both
  // directions fused in registers); horiz_final consumes it (block-local
  // lines) and overwrites with the final 4-way max. No ws use.
  vert_both<<<NCOL / CPB, 1024, 0, stream>>>(x, g0, g1, out);
  horiz_final<<<NROW / 4, 256, 0, stream>>>(x, g2, g3, out, out);
}

// Round 6
// 262.121 us; speedup vs baseline: 1.0059x; 1.0031x over previous
//
#include <hip/hip_runtime.h>

// (B,C,H,W) = (4,16,320,640), fp32 throughout.
constexpr int Bn = 4;
constexpr int Cn = 16;
constexpr int Hn = 320;
constexpr int Wn = 640;
constexpr int NCOL = Bn * Cn * Wn;   // 40960 vertical columns
constexpr int NROW = Bn * Cn * Hn;   // 20480 horizontal rows

// ---------------------------------------------------------------------------
// Vertical scan, both directions, ZERO-SPILL design.
// History: rounds 0-2 kept 40-88 floats live across the stitch barrier; the
// allocator pinned VGPR_Count at 32-56 across three restructures and spilled
// to scratch. Scratch stayed L2-resident (WRITE_SIZE exactly 51200 KB every
// round -> no HBM leakage) so the cost was invisible to TCC counters: ~160MB
// of hidden L2 round-trips, dur pinned at ~71us, VALUBusy 6%.
//
// This version caps true live state at ~26-28 regs so even a 32-VGPR
// allocation cannot spill:
//   P1 DOWN scan (ascending): load x,g0; live = rd0..9 + pd0..9 (~26).
//   barrier; wave-0 stitch of DOWN summaries; barrier.
//   P2 fixup d_i = fma(pd,cd,rd) -> 40KB LDS stash (rd/pd die here).
//      UP scan (descending): re-load x (L2-hot 40KB tile) + g1;
//      live = yu0..9 + pu0..9 (~26).
//   barrier; wave-0 stitch of UP summaries; barrier.
//   P3 final (descending): u = fma(pu,cu,yu); vm = max(dstash, u).
// LDS: 16KB summaries + 40KB stash = 56KB -> 2 blocks/CU.
// Coalescing unchanged: 128B contiguous per 32-lane group per instruction.
// Recurrence: y = g*y_prev + x*(1-g) == fma(g, y_prev - x, x); g:=0 at head.
// ---------------------------------------------------------------------------
constexpr int HS = 10;               // rows per segment (320 = 32*10)
constexpr int NS = 32;               // segments per column
constexpr int CPB = 32;              // columns per block
constexpr int GPW = Wn / CPB;        // 20 column-groups per image width

#define REP10(M) M(0) M(1) M(2) M(3) M(4) M(5) M(6) M(7) M(8) M(9)
#define REP10R(M) M(9) M(8) M(7) M(6) M(5) M(4) M(3) M(2) M(1) M(0)

__global__ __launch_bounds__(1024, 2) void vert_both(
    const float* __restrict__ x, const float* __restrict__ g0,
    const float* __restrict__ g1, float* __restrict__ vm) {
  __shared__ float As[NS][CPB], Bs[NS][CPB];        // 8 KB (reused per dir)
  __shared__ float dstash[NS][HS][CPB];             // 40 KB
  const int grp = blockIdx.x;              // 1280 groups
  const int bc = grp / GPW;
  const int w0 = (grp % GPW) * CPB;
  const int s = threadIdx.x >> 5;          // segment 0..31
  const int l = threadIdx.x & 31;          // column-in-group 0..31
  const int colbase = bc * (Hn * Wn) + w0 + l;   // < 2^24, int is fine
  const int base = colbase + (s * HS) * Wn;

  // ---------------- P1: DOWN local scan (g0, rows ascending) ----------------
#define DECLD(i) float rd##i, pd##i;
  REP10(DECLD)
#undef DECLD
  {
    int off = base;
    float yy = 0.0f, pp = 1.0f;
#define DSTEP(i)                                                      \
    {                                                                 \
      float xv = x[off];                                              \
      float gv = g0[off];                                             \
      float bb = (s == 0 && i == 0) ? 0.0f : gv;                      \
      yy = fmaf(bb, yy - xv, xv);                                     \
      pp *= bb;                                                       \
      rd##i = yy;                                                     \
      pd##i = pp;                                                     \
      off += Wn;                                                      \
    }
    REP10(DSTEP)
#undef DSTEP
    As[s][l] = yy;
    Bs[s][l] = pp;
  }
  __syncthreads();
  if (s == 0) {                            // wave 0, lanes 0-31: DOWN stitch
    float c = 0.0f;
#pragma unroll
    for (int ss = 0; ss < NS; ++ss) {
      float a = As[ss][l], b = Bs[ss][l];
      As[ss][l] = c;                       // carry-in for segment ss
      c = fmaf(b, c, a);
    }
  }
  __syncthreads();

  // ------- P2: fixup DOWN into LDS stash (rd/pd die); UP local scan -------
  {
    const float cd = As[s][l];
#define STASH(i) dstash[s][i][l] = fmaf(pd##i, cd, rd##i);
    REP10(STASH)
#undef STASH
  }
  __syncthreads();                         // As/Bs reuse for UP summaries

#define DECLU(i) float yu##i, pu##i;
  REP10(DECLU)
#undef DECLU
  {
    int off = base + (HS - 1) * Wn;
    float yy = 0.0f, pp = 1.0f;
#define USTEP(i)                                                      \
    {                                                                 \
      float xv = x[off];                                              \
      float gv = g1[off];                                             \
      float bb = (s == NS - 1 && i == HS - 1) ? 0.0f : gv;            \
      yy = fmaf(bb, yy - xv, xv);                                     \
      pp *= bb;                                                       \
      yu##i = yy;                                                     \
      pu##i = pp;                                                     \
      off -= Wn;                                                      \
    }
    REP10R(USTEP)
#undef USTEP
    As[s][l] = yy;
    Bs[s][l] = pp;
  }
  __syncthreads();
  if (s == 0) {                            // wave 0, lanes 0-31: UP stitch
    float c = 0.0f;
#pragma unroll
    for (int ss = NS - 1; ss >= 0; --ss) {
      float a = As[ss][l], b = Bs[ss][l];
      As[ss][l] = c;                       // carry-in from below
      c = fmaf(b, c, a);
    }
  }
  __syncthreads();

  // ---------- P3: UP fixup + max with stashed DOWN + single store ----------
  {
    const float cu = As[s][l];
    int off = base + (HS - 1) * Wn;
#define FSTEP(i)                                                      \
    {                                                                 \
      float u = fmaf(pu##i, cu, yu##i);                               \
      vm[off] = fmaxf(dstash[s][i][l], u);                            \
      off -= Wn;                                                      \
    }
    REP10R(FSTEP)
#undef FSTEP
  }
}

// ---------------------------------------------------------------------------
// Horizontal + final: block = 256 threads = 4 waves, 4 consecutive rows.
// Stage x/g2/g3 into LDS with coalesced float4 loads; prefetch vm(=out) into
// registers at the same time. One wave per row does the lane-segmented scan
// (WSEG=10) from LDS with one 6-step shuffle scan of (A,B) per direction.
// Final: out = max(r_right, r_left, vm) — same lines this block read.
// ---------------------------------------------------------------------------
constexpr int WSEG = 10;                   // 64 lanes * 10 = 640

__global__ __launch_bounds__(256) void horiz_final(
    const float* __restrict__ x, const float* __restrict__ g2,
    const float* __restrict__ g3, const float* __restrict__ vm,
    float* __restrict__ out) {
  __shared__ float xs[4 * Wn], rrs[4 * Wn], rls[4 * Wn];   // 30 KB
  const int tid = threadIdx.x, wv = tid >> 6, l = tid & 63;
  const size_t rowbase = (size_t)blockIdx.x * 4 * Wn;      // 4 rows contiguous

  const float4* xg = (const float4*)(x + rowbase);
  const float4* g2g = (const float4*)(g2 + rowbase);
  const float4* g3g = (const float4*)(g3 + rowbase);
  const float4* vm4 = (const float4*)(vm + rowbase);
  float4* xsv = (float4*)xs;
  float4* rrv = (float4*)rrs;
  float4* rlv = (float4*)rls;

  // ---- stage (coalesced float4); vm prefetched into registers ----
  const int i0 = tid, i1 = tid + 256, i2 = tid + 512;      // i2 valid if tid<128
  float4 v0, v1, v2;
  xsv[i0] = xg[i0]; rrv[i0] = g2g[i0]; rlv[i0] = g3g[i0]; v0 = vm4[i0];
  xsv[i1] = xg[i1]; rrv[i1] = g2g[i1]; rlv[i1] = g3g[i1]; v1 = vm4[i1];
  if (i2 < Wn) { xsv[i2] = xg[i2]; rrv[i2] = g2g[i2]; rlv[i2] = g3g[i2]; v2 = vm4[i2]; }
  __syncthreads();

  const int rb = wv * Wn + l * WSEG;
  float xl[WSEG], gl[WSEG], yl[WSEG], pl[WSEG];
#pragma unroll
  for (int i = 0; i < WSEG; ++i) { xl[i] = xs[rb + i]; gl[i] = rrs[rb + i]; }

  // ---- forward (r_right) ----
  {
    float y = 0.0f, p = 1.0f;
#pragma unroll
    for (int i = 0; i < WSEG; ++i) {
      float bb = (l == 0 && i == 0) ? 0.0f : gl[i];
      y = fmaf(bb, y - xl[i], xl[i]);
      p *= bb;
      yl[i] = y; pl[i] = p;
    }
    float A = y, B = p;
#pragma unroll
    for (int off = 1; off < 64; off <<= 1) {
      float Au = __shfl_up(A, off);
      float Bu = __shfl_up(B, off);
      if (l >= off) { A = fmaf(B, Au, A); B *= Bu; }
    }
    float c = __shfl_up(A, 1);
    if (l == 0) c = 0.0f;
#pragma unroll
    for (int i = 0; i < WSEG; ++i) rrs[rb + i] = fmaf(pl[i], c, yl[i]);
  }

  // ---- backward (r_left) ----
#pragma unroll
  for (int i = 0; i < WSEG; ++i) gl[i] = rls[rb + i];
  {
    float y = 0.0f, p = 1.0f;
#pragma unroll
    for (int i = WSEG - 1; i >= 0; --i) {
      float bb = (l == 63 && i == WSEG - 1) ? 0.0f : gl[i];
      y = fmaf(bb, y - xl[i], xl[i]);
      p *= bb;
      yl[i] = y; pl[i] = p;
    }
    float A = y, B = p;
#pragma unroll
    for (int off = 1; off < 64; off <<= 1) {
      float Ad = __shfl_down(A, off);
      float Bd = __shfl_down(B, off);
      if (l + off < 64) { A = fmaf(B, Ad, A); B *= Bd; }
    }
    float c = __shfl_down(A, 1);
    if (l == 63) c = 0.0f;
#pragma unroll
    for (int i = 0; i < WSEG; ++i) rls[rb + i] = fmaf(pl[i], c, yl[i]);
  }
  __syncthreads();

  // ---- fused final max + store (coalesced float4) ----
  float4* o4 = (float4*)(out + rowbase);
  {
    float4 a = rrv[i0], b = rlv[i0];
    float4 o;
    o.x = fmaxf(fmaxf(a.x, b.x), v0.x);
    o.y = fmaxf(fmaxf(a.y, b.y), v0.y);
    o.z = fmaxf(fmaxf(a.z, b.z), v0.z);
    o.w = fmaxf(fmaxf(a.w, b.w), v0.w);
    o4[i0] = o;
  }
  {
    float4 a = rrv[i1], b = rlv[i1];
    float4 o;
    o.x = fmaxf(fmaxf(a.x, b.x), v1.x);
    o.y = fmaxf(fmaxf(a.y, b.y), v1.y);
    o.z = fmaxf(fmaxf(a.z, b.z), v1.z);
    o.w = fmaxf(fmaxf(a.w, b.w), v1.w);
    o4[i1] = o;
  }
  if (i2 < Wn) {
    float4 a = rrv[i2], b = rlv[i2];
    float4 o;
    o.x = fmaxf(fmaxf(a.x, b.x), v2.x);
    o.y = fmaxf(fmaxf(a.y, b.y), v2.y);
    o.z = fmaxf(fmaxf(a.z, b.z), v2.z);
    o.w = fmaxf(fmaxf(a.w, b.w), v2.w);
    o4[i2] = o;
  }
}

extern "C" void kernel_launch(void* const* d_in, const int* in_sizes, int n_in,
                              void* d_out, int out_size, void* d_ws,
                              size_t ws_size, hipStream_t stream) {
  const float* x = (const float*)d_in[0];
  const float* g0 = (const float*)d_in[1];
  const float* g1 = (const float*)d_in[2];
  const float* g2 = (const float*)d_in[3];
  const float* g3 = (const float*)d_in[4];
  float* out = (float*)d_out;

  // vert_both writes max(r_down, r_up) into out (single store, DOWN values
  // staged through LDS); horiz_final consumes it (block-local lines) and
  // overwrites with the final 4-way max. No ws use.
  vert_both<<<NCOL / CPB, 1024, 0, stream>>>(x, g0, g1, out);
  horiz_final<<<NROW / 4, 256, 0, stream>>>(x, g2, g3, out, out);
}